// Round 11
// baseline (109.814 us; speedup 1.0000x reference)
//
#include <hip/hip_runtime.h>
#include <cstdint>
#include <cstddef>

typedef __bf16 bf16;
typedef __bf16 bf16x4_t __attribute__((ext_vector_type(4)));
typedef __bf16 bf16x8_t __attribute__((ext_vector_type(8)));
typedef float f32x4_t __attribute__((ext_vector_type(4)));

#define DEV static __device__ __forceinline__

DEV void gload16(const void* g, void* l) {
  __builtin_amdgcn_global_load_lds((const __attribute__((address_space(1))) void*)g,
                                   (__attribute__((address_space(3))) void*)l, 16, 0, 0);
}

DEV f32x4_t mfma16(bf16x8_t a, bf16x8_t b, f32x4_t c) {
  return __builtin_amdgcn_mfma_f32_16x16x32_bf16(a, b, c, 0, 0, 0);
}

#define BAR __builtin_amdgcn_s_barrier()
#define FENCE asm volatile("" ::: "memory")
#define VMC(n) asm volatile("s_waitcnt vmcnt(" #n ")" ::: "memory")

// ------------------------------------------------------------------
// Kernel 1: fp32 -> bf16 conversion of x and weights (unchanged).
// ------------------------------------------------------------------
__global__ __launch_bounds__(256) void k_convert(
    const float* __restrict__ x, const float* __restrict__ wq,
    const float* __restrict__ wk, const float* __restrict__ wv,
    const float* __restrict__ wl,
    bf16* __restrict__ xb, bf16* __restrict__ wqkvb, bf16* __restrict__ wlb) {
  const size_t M1 = (size_t)1 << 20;
  size_t i = ((size_t)blockIdx.x * 256 + threadIdx.x) * 4;
  const float* src; bf16* dst; size_t off;
  if (i < 4 * M1)      { src = x;  dst = xb;           off = i; }
  else if (i < 5 * M1) { src = wq; dst = wqkvb;        off = i - 4 * M1; }
  else if (i < 6 * M1) { src = wk; dst = wqkvb + M1;   off = i - 5 * M1; }
  else if (i < 7 * M1) { src = wv; dst = wqkvb + 2*M1; off = i - 6 * M1; }
  else                 { src = wl; dst = wlb;          off = i - 7 * M1; }
  f32x4_t v = *(const f32x4_t*)&src[off];
  bf16x4_t o;
  o[0] = (bf16)v[0]; o[1] = (bf16)v[1]; o[2] = (bf16)v[2]; o[3] = (bf16)v[3];
  *(bf16x4_t*)&dst[off] = o;
}

// ------------------------------------------------------------------
// Kernel 2: QKV projection (unchanged — parked at its structure
// ceiling: 6 schedule/tile variants all land 41-45us).
// ------------------------------------------------------------------
__global__ __launch_bounds__(256) void k_gemm_qkv(
    const bf16* __restrict__ W, const bf16* __restrict__ Xb,
    const float* __restrict__ bq, const float* __restrict__ bk,
    const float* __restrict__ bv,
    bf16* __restrict__ Q, bf16* __restrict__ Kc, bf16* __restrict__ VT) {
  __shared__ alignas(16) bf16 smem[16384];
  bf16* lA = smem;
  bf16* lB = smem + 8192;
  const int tid = threadIdx.x, wave = tid >> 6, lane = tid & 63;
  const int wm = (wave >> 1) * 64, wn = (wave & 1) * 64;
  const int fr = lane & 15, fg = lane >> 4;
  const int csw = (((lane & 7) ^ (lane >> 3)) << 3);
  const int m0 = blockIdx.x * 128, n0 = blockIdx.y * 128;

  f32x4_t acc[4][4];
  const f32x4_t vzero = {0.f, 0.f, 0.f, 0.f};
#pragma unroll
  for (int a = 0; a < 4; ++a)
#pragma unroll
    for (int c = 0; c < 4; ++c) acc[a][c] = vzero;

  const int rowoff = wave * 8 + (lane >> 3);

  for (int kt = 0; kt < 16; ++kt) {
#pragma unroll
    for (int i = 0; i < 4; ++i) {
      gload16(W + (size_t)(m0 + i * 32 + rowoff) * 1024 + kt * 64 + csw,
              &lA[(i * 32 + wave * 8) * 64]);
      gload16(Xb + (size_t)(n0 + i * 32 + rowoff) * 1024 + kt * 64 + csw,
              &lB[(i * 32 + wave * 8) * 64]);
    }
    __syncthreads();
    bf16x8_t af[4][2], bfr[4][2];
#pragma unroll
    for (int mi = 0; mi < 4; ++mi)
#pragma unroll
      for (int ks = 0; ks < 2; ++ks) {
        const int r = wm + mi * 16 + fr;
        af[mi][ks] = *(const bf16x8_t*)
            &lA[r * 64 + ((((ks << 2) + fg) ^ (fr & 7)) << 3)];
      }
#pragma unroll
    for (int ni = 0; ni < 4; ++ni)
#pragma unroll
      for (int ks = 0; ks < 2; ++ks) {
        const int r = wn + ni * 16 + fr;
        bfr[ni][ks] = *(const bf16x8_t*)
            &lB[r * 64 + ((((ks << 2) + fg) ^ (fr & 7)) << 3)];
      }
    __builtin_amdgcn_s_setprio(1);
#pragma unroll
    for (int ks = 0; ks < 2; ++ks)
#pragma unroll
      for (int mi = 0; mi < 4; ++mi)
#pragma unroll
        for (int ni = 0; ni < 4; ++ni)
          acc[mi][ni] = mfma16(af[mi][ks], bfr[ni][ks], acc[mi][ni]);
    __builtin_amdgcn_s_setprio(0);
    __syncthreads();
  }

  const int region = m0 >> 10;
  const float* bp = (region == 0) ? bq : ((region == 1) ? bk : bv);
  if (region < 2) {
    bf16* QK = (region == 0) ? Q : Kc;
#pragma unroll
    for (int mi = 0; mi < 4; ++mi) {
      const int f = (m0 & 1023) + wm + mi * 16 + fg * 4;
      const int h = f >> 6, d = f & 63;
#pragma unroll
      for (int ni = 0; ni < 4; ++ni) {
        const int t = n0 + wn + ni * 16 + fr;
        const int b = t >> 10, s = t & 1023;
        const int bh = b * 16 + h;
        f32x4_t v = acc[mi][ni];
        bf16x4_t o;
#pragma unroll
        for (int j = 0; j < 4; ++j) o[j] = (bf16)(v[j] + bp[f + j]);
        *(bf16x4_t*)&QK[((size_t)bh * 1024 + s) * 64 + d] = o;
      }
    }
  } else {
#pragma unroll
    for (int mi = 0; mi < 4; ++mi) {
      const int dl = wm + mi * 16 + fg * 4;
      const int floc = (m0 & 1023) + dl;
#pragma unroll
      for (int ni = 0; ni < 4; ++ni) {
        const int sl = wn + ni * 16 + fr;
        f32x4_t v = acc[mi][ni];
#pragma unroll
        for (int j = 0; j < 4; ++j) {
          const int d = dl + j;
          smem[d * 128 + (sl ^ ((d & 7) << 3))] = (bf16)(v[j] + bp[floc + j]);
        }
      }
    }
    __syncthreads();
    const int b = n0 >> 10;
#pragma unroll
    for (int i = 0; i < 8; ++i) {
      const int d = i * 16 + (tid >> 4);
      const int c = tid & 15;
      bf16x8_t vv = *(const bf16x8_t*)&smem[d * 128 + ((c ^ (d & 7)) << 3)];
      const int floc = (m0 & 1023) + d;
      const int h = floc >> 6, dd = floc & 63;
      const int sg = (n0 & 1023) + c * 8;
      *(bf16x8_t*)&VT[((size_t)(b * 16 + h) * 64 + dd) * 1024 + sg] = vv;
    }
  }
}

// ------------------------------------------------------------------
// 128x128 2-phase double-buffered mainloop (unchanged, k_gemm_out).
// ------------------------------------------------------------------
DEV void gemm_mainloop(const bf16* __restrict__ A, const bf16* __restrict__ B,
                       int m0, int n0,
                       bf16 (*lA)[128 * 64], bf16 (*lB)[128 * 64],
                       f32x4_t (&acc)[4][4]) {
  const int tid = threadIdx.x, wave = tid >> 6, lane = tid & 63;
  const int wm = (wave >> 1) * 64, wn = (wave & 1) * 64;
  const int fr = lane & 15, fg = lane >> 4;
  const int rowoff = wave * 8 + (lane >> 3);
  const int csw = (((lane & 7) ^ (lane >> 3)) << 3);

  auto STAGE = [&](int buf, int kt) {
#pragma unroll
    for (int i = 0; i < 4; ++i) {
      gload16(A + (size_t)(m0 + i * 32 + rowoff) * 1024 + kt * 64 + csw,
              &lA[buf][(i * 32 + wave * 8) * 64]);
      gload16(B + (size_t)(n0 + i * 32 + rowoff) * 1024 + kt * 64 + csw,
              &lB[buf][(i * 32 + wave * 8) * 64]);
    }
  };

  auto COMPUTE = [&](int buf) {
    bf16x8_t af[4][2], bfr[4][2];
#pragma unroll
    for (int mi = 0; mi < 4; ++mi)
#pragma unroll
      for (int ks = 0; ks < 2; ++ks) {
        const int r = wm + mi * 16 + fr;
        af[mi][ks] = *(const bf16x8_t*)
            &lA[buf][r * 64 + ((((ks << 2) + fg) ^ (fr & 7)) << 3)];
      }
#pragma unroll
    for (int ni = 0; ni < 4; ++ni)
#pragma unroll
      for (int ks = 0; ks < 2; ++ks) {
        const int r = wn + ni * 16 + fr;
        bfr[ni][ks] = *(const bf16x8_t*)
            &lB[buf][r * 64 + ((((ks << 2) + fg) ^ (fr & 7)) << 3)];
      }
    __builtin_amdgcn_s_setprio(1);
#pragma unroll
    for (int ks = 0; ks < 2; ++ks)
#pragma unroll
      for (int mi = 0; mi < 4; ++mi)
#pragma unroll
        for (int ni = 0; ni < 4; ++ni)
          acc[mi][ni] = mfma16(af[mi][ks], bfr[ni][ks], acc[mi][ni]);
    __builtin_amdgcn_s_setprio(0);
  };

  STAGE(0, 0);
  STAGE(1, 1);
  for (int t = 0; t < 15; ++t) {
    asm volatile("s_waitcnt vmcnt(8)" ::: "memory");
    __builtin_amdgcn_s_barrier();
    COMPUTE(t & 1);
    __builtin_amdgcn_s_barrier();
    if (t < 14) STAGE(t & 1, t + 2);
  }
  asm volatile("s_waitcnt vmcnt(0)" ::: "memory");
  __builtin_amdgcn_s_barrier();
  COMPUTE(1);
}

// ------------------------------------------------------------------
// Kernel 3 (CHANGED): swapped-QK^T in-register-P attention, 4-wave.
//  - lsum vectorized into f32x4 slots (breaks the 32-deep serial
//    v_add chain per tile into 4-way ILP; reassociation of positives).
//  - epilogue: O transposed through per-wave LDS (reusing the K/V
//    buffers after one barrier; XOR-swizzled both sides) ->
//    coalesced f32x4 X-loads and bf16x8 ATTB stores instead of
//    32 scalar 4B loads + 32 scalar 2B stores per thread.
// ------------------------------------------------------------------
__global__ __launch_bounds__(256) void k_attn(
    const bf16* __restrict__ Q, const bf16* __restrict__ K,
    const bf16* __restrict__ VT, const float* __restrict__ X,
    bf16* __restrict__ ATTB) {
  __shared__ alignas(16) bf16 sm[16384];   // lK[2] | lV[2], 32 KB
  const int tid = threadIdx.x, wave = tid >> 6, lane = tid & 63;
  const int bh = blockIdx.x, qt = blockIdx.y;
  const int q0 = qt * 128 + wave * 32;
  const int fr = lane & 15, fg = lane >> 4;
  const int rx = (fr & 7) << 3;
  const f32x4_t vzero = {0.f, 0.f, 0.f, 0.f};

  // Q fragments (B operand of swapped QK^T)
  bf16x8_t qf[2][2];
#pragma unroll
  for (int qi = 0; qi < 2; ++qi)
#pragma unroll
    for (int ks = 0; ks < 2; ++ks)
      qf[qi][ks] = *(const bf16x8_t*)
          &Q[((size_t)bh * 1024 + q0 + qi * 16 + fr) * 64 + ks * 32 + fg * 8];

  f32x4_t oacc[2][4];
  f32x4_t lsum4[2] = {vzero, vzero};
#pragma unroll
  for (int qi = 0; qi < 2; ++qi)
#pragma unroll
    for (int dj = 0; dj < 4; ++dj) oacc[qi][dj] = vzero;

  const int srow = lane >> 3;
  const int scolsw = (((lane & 7) ^ srow) * 8);

  auto STAGE = [&](int buf, int kv) {
    bf16* dK = sm + buf * 4096;
    bf16* dV = sm + 8192 + buf * 4096;
#pragma unroll
    for (int i = 0; i < 2; ++i) {
      const int c = wave * 2 + i;
      gload16(&K[((size_t)bh * 1024 + kv * 64 + c * 8 + srow) * 64 + scolsw],
              &dK[c * 512]);
      gload16(&VT[((size_t)bh * 64 + c * 8 + srow) * 1024 + kv * 64 + scolsw],
              &dV[c * 512]);
    }
  };

  auto TILE = [&](int cur) {
    const bf16* sK = sm + cur * 4096;
    const bf16* sV = sm + 8192 + cur * 4096;
    // K fragments (A operand): rows kv = kj*16+fr
    bf16x8_t kb[4][2];
#pragma unroll
    for (int kj = 0; kj < 4; ++kj)
#pragma unroll
      for (int ks = 0; ks < 2; ++ks) {
        const int r = kj * 16 + fr;
        kb[kj][ks] = *(const bf16x8_t*)&sK[r * 64 + ((ks * 32 + fg * 8) ^ rx)];
      }
    // S^T = K @ Q^T
    f32x4_t s[2][4];
#pragma unroll
    for (int qi = 0; qi < 2; ++qi)
#pragma unroll
      for (int kj = 0; kj < 4; ++kj) {
        f32x4_t z = vzero;
#pragma unroll
        for (int ks = 0; ks < 2; ++ks) z = mfma16(kb[kj][ks], qf[qi][ks], z);
        s[qi][kj] = z;
      }

    // V fragments (B operand of PV) with the P-matching k-map
    bf16x8_t vb[4][2];
#pragma unroll
    for (int dj = 0; dj < 4; ++dj)
#pragma unroll
      for (int ks = 0; ks < 2; ++ks) {
        const int r = dj * 16 + fr;
        const int c0 = ks * 32 + fg * 4;
        const int e0 = (c0 & 7) | ((((c0 >> 3) ^ (r & 7))) << 3);
        const int c1 = c0 + 16;
        const int e1 = (c1 & 7) | ((((c1 >> 3) ^ (r & 7))) << 3);
        bf16x4_t lo = *(const bf16x4_t*)&sV[r * 64 + e0];
        bf16x4_t hi = *(const bf16x4_t*)&sV[r * 64 + e1];
        bf16x8_t vv;
#pragma unroll
        for (int j = 0; j < 4; ++j) { vv[j] = lo[j]; vv[4 + j] = hi[j]; }
        vb[dj][ks] = vv;
      }

    // in-register softmax; lsum4 j-sliced (4-way ILP), ROUNDED bf16 p
    bf16x8_t paf[2][2];
#pragma unroll
    for (int qi = 0; qi < 2; ++qi)
#pragma unroll
      for (int ks = 0; ks < 2; ++ks) {
        bf16x8_t pv;
#pragma unroll
        for (int h2 = 0; h2 < 2; ++h2)
#pragma unroll
          for (int j = 0; j < 4; ++j) {
            bf16 pb = (bf16)__expf(s[qi][2 * ks + h2][j]);
            lsum4[qi][j] += (float)pb;
            pv[h2 * 4 + j] = pb;
          }
        paf[qi][ks] = pv;
      }

    // O += P @ V
#pragma unroll
    for (int qi = 0; qi < 2; ++qi)
#pragma unroll
      for (int dj = 0; dj < 4; ++dj)
#pragma unroll
        for (int ks = 0; ks < 2; ++ks)
          oacc[qi][dj] = mfma16(paf[qi][ks], vb[dj][ks], oacc[qi][dj]);
  };

  STAGE(0, 0);
  STAGE(1, 1);
  for (int kv = 0; kv < 15; ++kv) {
    VMC(4); BAR; FENCE;
    TILE(kv & 1);
    BAR; FENCE;
    if (kv < 14) STAGE(kv & 1, kv + 2);
  }
  VMC(0); BAR; FENCE;
  TILE(1);

  // row-sum: horizontal, then across fg groups, then redistribute
  float lsum[2];
#pragma unroll
  for (int qi = 0; qi < 2; ++qi) {
    lsum[qi] = (lsum4[qi][0] + lsum4[qi][1]) + (lsum4[qi][2] + lsum4[qi][3]);
    lsum[qi] += __shfl_xor(lsum[qi], 16);
    lsum[qi] += __shfl_xor(lsum[qi], 32);
  }
  float rs[2][4];
#pragma unroll
  for (int qi = 0; qi < 2; ++qi)
#pragma unroll
    for (int j = 0; j < 4; ++j)
      rs[qi][j] = __shfl(lsum[qi], fg * 4 + j);

  // ---- epilogue: transpose O through per-wave LDS for coalescing ----
  BAR;  // all waves done reading K/V buffers; safe to repurpose sm
  bf16* lT = sm + wave * 2048;   // [32 rows][64 d], XOR-swizzled
#pragma unroll
  for (int qi = 0; qi < 2; ++qi)
#pragma unroll
    for (int dj = 0; dj < 4; ++dj)
#pragma unroll
      for (int j = 0; j < 4; ++j) {
        const int m = qi * 16 + fg * 4 + j;
        const int d = dj * 16 + fr;
        lT[m * 64 + (d ^ ((m & 7) << 3))] =
            (bf16)(oacc[qi][dj][j] / rs[qi][j] * 0.125f);
      }
  // wave-private region: no barrier needed (lgkmcnt auto-inserted)
  const int b = bh >> 4, h = bh & 15;
#pragma unroll
  for (int i = 0; i < 4; ++i) {
    const int row = i * 8 + (lane >> 3);
    const int col = (lane & 7) * 8;
    bf16x8_t av = *(const bf16x8_t*)&lT[row * 64 + (col ^ ((row & 7) << 3))];
    const size_t tok = (size_t)b * 1024 + q0 + row;
    const size_t fx = (size_t)h * 64 + col;
    f32x4_t x0 = *(const f32x4_t*)&X[tok * 1024 + fx];
    f32x4_t x1 = *(const f32x4_t*)&X[tok * 1024 + fx + 4];
    bf16x8_t o;
#pragma unroll
    for (int j = 0; j < 4; ++j) {
      o[j] = (bf16)((float)av[j] + x0[j]);
      o[4 + j] = (bf16)((float)av[4 + j] + x1[j]);
    }
    *(bf16x8_t*)&ATTB[tok * 1024 + fx] = o;
  }
}

// ------------------------------------------------------------------
// Kernel 4: output projection (unchanged; bf16 Y).
// ------------------------------------------------------------------
__global__ __launch_bounds__(256, 2) void k_gemm_out(
    const bf16* __restrict__ Wl, const bf16* __restrict__ Ax,
    const float* __restrict__ bl, bf16* __restrict__ Y) {
  __shared__ alignas(16) bf16 lA[2][128 * 64];
  __shared__ alignas(16) bf16 lB[2][128 * 64];
  const f32x4_t vzero = {0.f, 0.f, 0.f, 0.f};
  f32x4_t acc[4][4];
#pragma unroll
  for (int a = 0; a < 4; ++a)
#pragma unroll
    for (int c = 0; c < 4; ++c) acc[a][c] = vzero;
  const int m0 = blockIdx.x * 128, n0 = blockIdx.y * 128;
  gemm_mainloop(Wl, Ax, m0, n0, lA, lB, acc);

  const int tid = threadIdx.x, wave = tid >> 6, lane = tid & 63;
  const int wm = (wave >> 1) * 64, wn = (wave & 1) * 64;
  const int fr = lane & 15, fg = lane >> 4;
#pragma unroll
  for (int mi = 0; mi < 4; ++mi) {
    const int f = m0 + wm + mi * 16 + fg * 4;
#pragma unroll
    for (int ni = 0; ni < 4; ++ni) {
      const int t = n0 + wn + ni * 16 + fr;
      f32x4_t v = acc[mi][ni];
      bf16x4_t o;
#pragma unroll
      for (int j = 0; j < 4; ++j) o[j] = (bf16)(v[j] + bl[f + j]);
      *(bf16x4_t*)&Y[(size_t)t * 1024 + f] = o;
    }
  }
}

// ------------------------------------------------------------------
// Kernel 5: LayerNorm (unchanged; reads bf16 Y).
// ------------------------------------------------------------------
__global__ __launch_bounds__(256) void k_ln(
    const bf16* __restrict__ Y, const float* __restrict__ g,
    const float* __restrict__ bta, float* __restrict__ OUT) {
  const int row = blockIdx.x, tid = threadIdx.x;
  const bf16* y = Y + (size_t)row * 1024;
  bf16x4_t yv = *(const bf16x4_t*)&y[tid * 4];
  f32x4_t v;
#pragma unroll
  for (int j = 0; j < 4; ++j) v[j] = (float)yv[j];
  float s = v[0] + v[1] + v[2] + v[3];
  float s2 = v[0]*v[0] + v[1]*v[1] + v[2]*v[2] + v[3]*v[3];
#pragma unroll
  for (int m = 1; m < 64; m <<= 1) {
    s += __shfl_xor(s, m);
    s2 += __shfl_xor(s2, m);
  }
  __shared__ float ps[4], ps2[4];
  const int wave = tid >> 6, lane = tid & 63;
  if (lane == 0) { ps[wave] = s; ps2[wave] = s2; }
  __syncthreads();
  s = ps[0] + ps[1] + ps[2] + ps[3];
  s2 = ps2[0] + ps2[1] + ps2[2] + ps2[3];
  const float mu = s * (1.f / 1024.f);
  const float var = s2 * (1.f / 1024.f) - mu * mu;
  const float rs = rsqrtf(var + 1e-5f);
  f32x4_t gg = *(const f32x4_t*)&g[tid * 4];
  f32x4_t bb = *(const f32x4_t*)&bta[tid * 4];
  f32x4_t o;
#pragma unroll
  for (int j = 0; j < 4; ++j) o[j] = (v[j] - mu) * rs * gg[j] + bb[j];
  *(f32x4_t*)&OUT[(size_t)row * 1024 + tid * 4] = o;
}

// ------------------------------------------------------------------
extern "C" void kernel_launch(void* const* d_in, const int* in_sizes, int n_in,
                              void* d_out, int out_size, void* d_ws, size_t ws_size,
                              hipStream_t stream) {
  (void)in_sizes; (void)n_in; (void)out_size; (void)ws_size;
  const float* x   = (const float*)d_in[0];
  const float* wq  = (const float*)d_in[1];
  const float* bq  = (const float*)d_in[2];
  const float* wk  = (const float*)d_in[3];
  const float* bk  = (const float*)d_in[4];
  const float* wv  = (const float*)d_in[5];
  const float* bv  = (const float*)d_in[6];
  const float* wl  = (const float*)d_in[7];
  const float* bl  = (const float*)d_in[8];
  const float* lng = (const float*)d_in[9];
  const float* lnb = (const float*)d_in[10];

  const size_t MB = (size_t)1 << 20;
  char* ws = (char*)d_ws;
  bf16* xb    = (bf16*)(ws);             // 8 MB  [0,8)
  bf16* wqkvb = (bf16*)(ws + 8 * MB);    // 6 MB  [8,14)
  bf16* wlb   = (bf16*)(ws + 14 * MB);   // 2 MB  [14,16)
  bf16* Qb    = (bf16*)(ws + 16 * MB);   // 8 MB  [16,24)
  bf16* Kb    = (bf16*)(ws + 24 * MB);   // 8 MB  [24,32)
  bf16* VTb   = (bf16*)(ws + 32 * MB);   // 8 MB  [32,40)
  bf16* attb  = (bf16*)(ws + 40 * MB);   // 8 MB  [40,48)
  bf16* Y     = (bf16*)(ws + 16 * MB);   // 8 MB  [16,24) reuse: Q dead post-attn

  k_convert<<<dim3(8192), dim3(256), 0, stream>>>(x, wq, wk, wv, wl, xb, wqkvb, wlb);
  k_gemm_qkv<<<dim3(24, 32), dim3(256), 0, stream>>>(wqkvb, xb, bq, bk, bv, Qb, Kb, VTb);
  k_attn<<<dim3(64, 8), dim3(256), 0, stream>>>(Qb, Kb, VTb, x, attb);
  k_gemm_out<<<dim3(8, 32), dim3(256), 0, stream>>>(wlb, attb, bl, Y);
  k_ln<<<dim3(4096), dim3(256), 0, stream>>>(Y, lng, lnb, (float*)d_out);
}

// Round 12
// 104.975 us; speedup vs baseline: 1.0461x; 1.0461x over previous
//
#include <hip/hip_runtime.h>
#include <cstdint>
#include <cstddef>

typedef __bf16 bf16;
typedef __bf16 bf16x4_t __attribute__((ext_vector_type(4)));
typedef __bf16 bf16x8_t __attribute__((ext_vector_type(8)));
typedef float f32x4_t __attribute__((ext_vector_type(4)));

#define DEV static __device__ __forceinline__

DEV void gload16(const void* g, void* l) {
  __builtin_amdgcn_global_load_lds((const __attribute__((address_space(1))) void*)g,
                                   (__attribute__((address_space(3))) void*)l, 16, 0, 0);
}

DEV f32x4_t mfma16(bf16x8_t a, bf16x8_t b, f32x4_t c) {
  return __builtin_amdgcn_mfma_f32_16x16x32_bf16(a, b, c, 0, 0, 0);
}

#define BAR __builtin_amdgcn_s_barrier()
#define FENCE asm volatile("" ::: "memory")
#define VMC(n) asm volatile("s_waitcnt vmcnt(" #n ")" ::: "memory")

// ------------------------------------------------------------------
// Kernel 1: fp32 -> bf16 conversion of x and weights (unchanged).
// ------------------------------------------------------------------
__global__ __launch_bounds__(256) void k_convert(
    const float* __restrict__ x, const float* __restrict__ wq,
    const float* __restrict__ wk, const float* __restrict__ wv,
    const float* __restrict__ wl,
    bf16* __restrict__ xb, bf16* __restrict__ wqkvb, bf16* __restrict__ wlb) {
  const size_t M1 = (size_t)1 << 20;
  size_t i = ((size_t)blockIdx.x * 256 + threadIdx.x) * 4;
  const float* src; bf16* dst; size_t off;
  if (i < 4 * M1)      { src = x;  dst = xb;           off = i; }
  else if (i < 5 * M1) { src = wq; dst = wqkvb;        off = i - 4 * M1; }
  else if (i < 6 * M1) { src = wk; dst = wqkvb + M1;   off = i - 5 * M1; }
  else if (i < 7 * M1) { src = wv; dst = wqkvb + 2*M1; off = i - 6 * M1; }
  else                 { src = wl; dst = wlb;          off = i - 7 * M1; }
  f32x4_t v = *(const f32x4_t*)&src[off];
  bf16x4_t o;
  o[0] = (bf16)v[0]; o[1] = (bf16)v[1]; o[2] = (bf16)v[2]; o[3] = (bf16)v[3];
  *(bf16x4_t*)&dst[off] = o;
}

// ------------------------------------------------------------------
// Kernel 2: QKV projection (unchanged — parked at structure ceiling).
// ------------------------------------------------------------------
__global__ __launch_bounds__(256) void k_gemm_qkv(
    const bf16* __restrict__ W, const bf16* __restrict__ Xb,
    const float* __restrict__ bq, const float* __restrict__ bk,
    const float* __restrict__ bv,
    bf16* __restrict__ Q, bf16* __restrict__ Kc, bf16* __restrict__ VT) {
  __shared__ alignas(16) bf16 smem[16384];
  bf16* lA = smem;
  bf16* lB = smem + 8192;
  const int tid = threadIdx.x, wave = tid >> 6, lane = tid & 63;
  const int wm = (wave >> 1) * 64, wn = (wave & 1) * 64;
  const int fr = lane & 15, fg = lane >> 4;
  const int csw = (((lane & 7) ^ (lane >> 3)) << 3);
  const int m0 = blockIdx.x * 128, n0 = blockIdx.y * 128;

  f32x4_t acc[4][4];
  const f32x4_t vzero = {0.f, 0.f, 0.f, 0.f};
#pragma unroll
  for (int a = 0; a < 4; ++a)
#pragma unroll
    for (int c = 0; c < 4; ++c) acc[a][c] = vzero;

  const int rowoff = wave * 8 + (lane >> 3);

  for (int kt = 0; kt < 16; ++kt) {
#pragma unroll
    for (int i = 0; i < 4; ++i) {
      gload16(W + (size_t)(m0 + i * 32 + rowoff) * 1024 + kt * 64 + csw,
              &lA[(i * 32 + wave * 8) * 64]);
      gload16(Xb + (size_t)(n0 + i * 32 + rowoff) * 1024 + kt * 64 + csw,
              &lB[(i * 32 + wave * 8) * 64]);
    }
    __syncthreads();
    bf16x8_t af[4][2], bfr[4][2];
#pragma unroll
    for (int mi = 0; mi < 4; ++mi)
#pragma unroll
      for (int ks = 0; ks < 2; ++ks) {
        const int r = wm + mi * 16 + fr;
        af[mi][ks] = *(const bf16x8_t*)
            &lA[r * 64 + ((((ks << 2) + fg) ^ (fr & 7)) << 3)];
      }
#pragma unroll
    for (int ni = 0; ni < 4; ++ni)
#pragma unroll
      for (int ks = 0; ks < 2; ++ks) {
        const int r = wn + ni * 16 + fr;
        bfr[ni][ks] = *(const bf16x8_t*)
            &lB[r * 64 + ((((ks << 2) + fg) ^ (fr & 7)) << 3)];
      }
    __builtin_amdgcn_s_setprio(1);
#pragma unroll
    for (int ks = 0; ks < 2; ++ks)
#pragma unroll
      for (int mi = 0; mi < 4; ++mi)
#pragma unroll
        for (int ni = 0; ni < 4; ++ni)
          acc[mi][ni] = mfma16(af[mi][ks], bfr[ni][ks], acc[mi][ni]);
    __builtin_amdgcn_s_setprio(0);
    __syncthreads();
  }

  const int region = m0 >> 10;
  const float* bp = (region == 0) ? bq : ((region == 1) ? bk : bv);
  if (region < 2) {
    bf16* QK = (region == 0) ? Q : Kc;
#pragma unroll
    for (int mi = 0; mi < 4; ++mi) {
      const int f = (m0 & 1023) + wm + mi * 16 + fg * 4;
      const int h = f >> 6, d = f & 63;
#pragma unroll
      for (int ni = 0; ni < 4; ++ni) {
        const int t = n0 + wn + ni * 16 + fr;
        const int b = t >> 10, s = t & 1023;
        const int bh = b * 16 + h;
        f32x4_t v = acc[mi][ni];
        bf16x4_t o;
#pragma unroll
        for (int j = 0; j < 4; ++j) o[j] = (bf16)(v[j] + bp[f + j]);
        *(bf16x4_t*)&QK[((size_t)bh * 1024 + s) * 64 + d] = o;
      }
    }
  } else {
#pragma unroll
    for (int mi = 0; mi < 4; ++mi) {
      const int dl = wm + mi * 16 + fg * 4;
      const int floc = (m0 & 1023) + dl;
#pragma unroll
      for (int ni = 0; ni < 4; ++ni) {
        const int sl = wn + ni * 16 + fr;
        f32x4_t v = acc[mi][ni];
#pragma unroll
        for (int j = 0; j < 4; ++j) {
          const int d = dl + j;
          smem[d * 128 + (sl ^ ((d & 7) << 3))] = (bf16)(v[j] + bp[floc + j]);
        }
      }
    }
    __syncthreads();
    const int b = n0 >> 10;
#pragma unroll
    for (int i = 0; i < 8; ++i) {
      const int d = i * 16 + (tid >> 4);
      const int c = tid & 15;
      bf16x8_t vv = *(const bf16x8_t*)&smem[d * 128 + ((c ^ (d & 7)) << 3)];
      const int floc = (m0 & 1023) + d;
      const int h = floc >> 6, dd = floc & 63;
      const int sg = (n0 & 1023) + c * 8;
      *(bf16x8_t*)&VT[((size_t)(b * 16 + h) * 64 + dd) * 1024 + sg] = vv;
    }
  }
}

// ------------------------------------------------------------------
// Kernel 3: swapped-QK^T in-register-P attention — r10 scalar
// epilogue restored (LDS-transpose epilogue was perf-neutral and
// cost +0.012 absmax from the extra O rounding); lsum4 ILP kept.
// ------------------------------------------------------------------
__global__ __launch_bounds__(256) void k_attn(
    const bf16* __restrict__ Q, const bf16* __restrict__ K,
    const bf16* __restrict__ VT, const float* __restrict__ X,
    bf16* __restrict__ ATTB) {
  __shared__ alignas(16) bf16 sm[16384];   // lK[2] | lV[2], 32 KB
  const int tid = threadIdx.x, wave = tid >> 6, lane = tid & 63;
  const int bh = blockIdx.x, qt = blockIdx.y;
  const int q0 = qt * 128 + wave * 32;
  const int fr = lane & 15, fg = lane >> 4;
  const int rx = (fr & 7) << 3;
  const f32x4_t vzero = {0.f, 0.f, 0.f, 0.f};

  bf16x8_t qf[2][2];
#pragma unroll
  for (int qi = 0; qi < 2; ++qi)
#pragma unroll
    for (int ks = 0; ks < 2; ++ks)
      qf[qi][ks] = *(const bf16x8_t*)
          &Q[((size_t)bh * 1024 + q0 + qi * 16 + fr) * 64 + ks * 32 + fg * 8];

  f32x4_t oacc[2][4];
  f32x4_t lsum4[2] = {vzero, vzero};
#pragma unroll
  for (int qi = 0; qi < 2; ++qi)
#pragma unroll
    for (int dj = 0; dj < 4; ++dj) oacc[qi][dj] = vzero;

  const int srow = lane >> 3;
  const int scolsw = (((lane & 7) ^ srow) * 8);

  auto STAGE = [&](int buf, int kv) {
    bf16* dK = sm + buf * 4096;
    bf16* dV = sm + 8192 + buf * 4096;
#pragma unroll
    for (int i = 0; i < 2; ++i) {
      const int c = wave * 2 + i;
      gload16(&K[((size_t)bh * 1024 + kv * 64 + c * 8 + srow) * 64 + scolsw],
              &dK[c * 512]);
      gload16(&VT[((size_t)bh * 64 + c * 8 + srow) * 1024 + kv * 64 + scolsw],
              &dV[c * 512]);
    }
  };

  auto TILE = [&](int cur) {
    const bf16* sK = sm + cur * 4096;
    const bf16* sV = sm + 8192 + cur * 4096;
    bf16x8_t kb[4][2];
#pragma unroll
    for (int kj = 0; kj < 4; ++kj)
#pragma unroll
      for (int ks = 0; ks < 2; ++ks) {
        const int r = kj * 16 + fr;
        kb[kj][ks] = *(const bf16x8_t*)&sK[r * 64 + ((ks * 32 + fg * 8) ^ rx)];
      }
    f32x4_t s[2][4];
#pragma unroll
    for (int qi = 0; qi < 2; ++qi)
#pragma unroll
      for (int kj = 0; kj < 4; ++kj) {
        f32x4_t z = vzero;
#pragma unroll
        for (int ks = 0; ks < 2; ++ks) z = mfma16(kb[kj][ks], qf[qi][ks], z);
        s[qi][kj] = z;
      }

    bf16x8_t vb[4][2];
#pragma unroll
    for (int dj = 0; dj < 4; ++dj)
#pragma unroll
      for (int ks = 0; ks < 2; ++ks) {
        const int r = dj * 16 + fr;
        const int c0 = ks * 32 + fg * 4;
        const int e0 = (c0 & 7) | ((((c0 >> 3) ^ (r & 7))) << 3);
        const int c1 = c0 + 16;
        const int e1 = (c1 & 7) | ((((c1 >> 3) ^ (r & 7))) << 3);
        bf16x4_t lo = *(const bf16x4_t*)&sV[r * 64 + e0];
        bf16x4_t hi = *(const bf16x4_t*)&sV[r * 64 + e1];
        bf16x8_t vv;
#pragma unroll
        for (int j = 0; j < 4; ++j) { vv[j] = lo[j]; vv[4 + j] = hi[j]; }
        vb[dj][ks] = vv;
      }

    bf16x8_t paf[2][2];
#pragma unroll
    for (int qi = 0; qi < 2; ++qi)
#pragma unroll
      for (int ks = 0; ks < 2; ++ks) {
        bf16x8_t pv;
#pragma unroll
        for (int h2 = 0; h2 < 2; ++h2)
#pragma unroll
          for (int j = 0; j < 4; ++j) {
            bf16 pb = (bf16)__expf(s[qi][2 * ks + h2][j]);
            lsum4[qi][j] += (float)pb;
            pv[h2 * 4 + j] = pb;
          }
        paf[qi][ks] = pv;
      }

#pragma unroll
    for (int qi = 0; qi < 2; ++qi)
#pragma unroll
      for (int dj = 0; dj < 4; ++dj)
#pragma unroll
        for (int ks = 0; ks < 2; ++ks)
          oacc[qi][dj] = mfma16(paf[qi][ks], vb[dj][ks], oacc[qi][dj]);
  };

  STAGE(0, 0);
  STAGE(1, 1);
  for (int kv = 0; kv < 15; ++kv) {
    VMC(4); BAR; FENCE;
    TILE(kv & 1);
    BAR; FENCE;
    if (kv < 14) STAGE(kv & 1, kv + 2);
  }
  VMC(0); BAR; FENCE;
  TILE(1);

  float lsum[2];
#pragma unroll
  for (int qi = 0; qi < 2; ++qi) {
    lsum[qi] = (lsum4[qi][0] + lsum4[qi][1]) + (lsum4[qi][2] + lsum4[qi][3]);
    lsum[qi] += __shfl_xor(lsum[qi], 16);
    lsum[qi] += __shfl_xor(lsum[qi], 32);
  }
  float rs[2][4];
#pragma unroll
  for (int qi = 0; qi < 2; ++qi)
#pragma unroll
    for (int j = 0; j < 4; ++j)
      rs[qi][j] = __shfl(lsum[qi], fg * 4 + j);

  // scalar epilogue (r10): single rounding of (O/l*0.125 + x)
  const int b = bh >> 4, h = bh & 15;
#pragma unroll
  for (int qi = 0; qi < 2; ++qi)
#pragma unroll
    for (int dj = 0; dj < 4; ++dj)
#pragma unroll
      for (int j = 0; j < 4; ++j) {
        const int s_ = q0 + qi * 16 + fg * 4 + j;
        const int d_ = dj * 16 + fr;
        const size_t tok = (size_t)b * 1024 + s_;
        const size_t fidx = (size_t)h * 64 + d_;
        float val = oacc[qi][dj][j] / rs[qi][j] * 0.125f + X[tok * 1024 + fidx];
        ATTB[tok * 1024 + fidx] = (bf16)val;
      }
}

// ------------------------------------------------------------------
// Kernel 4 (REWORKED): output projection with 64(M)x128(N) tiles ->
// grid (16,32) = 512 blocks = 2 blocks/CU (was 256 = 1/CU: no TLP
// backfill through barriers — the r4 lesson applied to this kernel).
// Same 2-phase dbuf + counted vmcnt + swizzle; 6 gloads/wave/stage
// (2 A-chunks + 4 B-chunks) -> vmcnt(6). LDS 48 KB -> 2 blocks/CU.
// ------------------------------------------------------------------
__global__ __launch_bounds__(256, 2) void k_gemm_out(
    const bf16* __restrict__ Wl, const bf16* __restrict__ Ax,
    const float* __restrict__ bl, bf16* __restrict__ Y) {
  __shared__ alignas(16) bf16 lA[2][64 * 64];
  __shared__ alignas(16) bf16 lB[2][128 * 64];
  const int tid = threadIdx.x, wave = tid >> 6, lane = tid & 63;
  const int wm = (wave >> 1) * 32, wn = (wave & 1) * 64;
  const int fr = lane & 15, fg = lane >> 4;
  const int srow = lane >> 3;
  const int csw = (((lane & 7) ^ srow) << 3);
  const int m0 = blockIdx.x * 64, n0 = blockIdx.y * 128;

  f32x4_t acc[2][4];
  const f32x4_t vzero = {0.f, 0.f, 0.f, 0.f};
#pragma unroll
  for (int a = 0; a < 2; ++a)
#pragma unroll
    for (int c = 0; c < 4; ++c) acc[a][c] = vzero;

  auto STAGE = [&](int buf, int kt) {
#pragma unroll
    for (int i = 0; i < 2; ++i)   // A: 2 chunks of 8 rows per wave
      gload16(Wl + (size_t)(m0 + wave * 16 + i * 8 + srow) * 1024 + kt * 64 + csw,
              &lA[buf][(wave * 16 + i * 8) * 64]);
#pragma unroll
    for (int i = 0; i < 4; ++i)   // B: 4 chunks of 8 rows per wave
      gload16(Ax + (size_t)(n0 + wave * 32 + i * 8 + srow) * 1024 + kt * 64 + csw,
              &lB[buf][(wave * 32 + i * 8) * 64]);
  };

  auto COMPUTE = [&](int buf) {
    bf16x8_t af[2][2], bfr[4][2];
#pragma unroll
    for (int mi = 0; mi < 2; ++mi)
#pragma unroll
      for (int ks = 0; ks < 2; ++ks) {
        const int r = wm + mi * 16 + fr;
        af[mi][ks] = *(const bf16x8_t*)
            &lA[buf][r * 64 + ((((ks << 2) + fg) ^ (fr & 7)) << 3)];
      }
#pragma unroll
    for (int ni = 0; ni < 4; ++ni)
#pragma unroll
      for (int ks = 0; ks < 2; ++ks) {
        const int r = wn + ni * 16 + fr;
        bfr[ni][ks] = *(const bf16x8_t*)
            &lB[buf][r * 64 + ((((ks << 2) + fg) ^ (fr & 7)) << 3)];
      }
    __builtin_amdgcn_s_setprio(1);
#pragma unroll
    for (int ks = 0; ks < 2; ++ks)
#pragma unroll
      for (int mi = 0; mi < 2; ++mi)
#pragma unroll
        for (int ni = 0; ni < 4; ++ni)
          acc[mi][ni] = mfma16(af[mi][ks], bfr[ni][ks], acc[mi][ni]);
    __builtin_amdgcn_s_setprio(0);
  };

  STAGE(0, 0);
  STAGE(1, 1);
  for (int t = 0; t < 15; ++t) {
    asm volatile("s_waitcnt vmcnt(6)" ::: "memory");
    __builtin_amdgcn_s_barrier();
    COMPUTE(t & 1);
    __builtin_amdgcn_s_barrier();
    if (t < 14) STAGE(t & 1, t + 2);
  }
  asm volatile("s_waitcnt vmcnt(0)" ::: "memory");
  __builtin_amdgcn_s_barrier();
  COMPUTE(1);

#pragma unroll
  for (int mi = 0; mi < 2; ++mi) {
    const int f = m0 + wm + mi * 16 + fg * 4;
#pragma unroll
    for (int ni = 0; ni < 4; ++ni) {
      const int t = n0 + wn + ni * 16 + fr;
      f32x4_t v = acc[mi][ni];
      bf16x4_t o;
#pragma unroll
      for (int j = 0; j < 4; ++j) o[j] = (bf16)(v[j] + bl[f + j]);
      *(bf16x4_t*)&Y[(size_t)t * 1024 + f] = o;
    }
  }
}

// ------------------------------------------------------------------
// Kernel 5: LayerNorm (unchanged; reads bf16 Y).
// ------------------------------------------------------------------
__global__ __launch_bounds__(256) void k_ln(
    const bf16* __restrict__ Y, const float* __restrict__ g,
    const float* __restrict__ bta, float* __restrict__ OUT) {
  const int row = blockIdx.x, tid = threadIdx.x;
  const bf16* y = Y + (size_t)row * 1024;
  bf16x4_t yv = *(const bf16x4_t*)&y[tid * 4];
  f32x4_t v;
#pragma unroll
  for (int j = 0; j < 4; ++j) v[j] = (float)yv[j];
  float s = v[0] + v[1] + v[2] + v[3];
  float s2 = v[0]*v[0] + v[1]*v[1] + v[2]*v[2] + v[3]*v[3];
#pragma unroll
  for (int m = 1; m < 64; m <<= 1) {
    s += __shfl_xor(s, m);
    s2 += __shfl_xor(s2, m);
  }
  __shared__ float ps[4], ps2[4];
  const int wave = tid >> 6, lane = tid & 63;
  if (lane == 0) { ps[wave] = s; ps2[wave] = s2; }
  __syncthreads();
  s = ps[0] + ps[1] + ps[2] + ps[3];
  s2 = ps2[0] + ps2[1] + ps2[2] + ps2[3];
  const float mu = s * (1.f / 1024.f);
  const float var = s2 * (1.f / 1024.f) - mu * mu;
  const float rs = rsqrtf(var + 1e-5f);
  f32x4_t gg = *(const f32x4_t*)&g[tid * 4];
  f32x4_t bb = *(const f32x4_t*)&bta[tid * 4];
  f32x4_t o;
#pragma unroll
  for (int j = 0; j < 4; ++j) o[j] = (v[j] - mu) * rs * gg[j] + bb[j];
  *(f32x4_t*)&OUT[(size_t)row * 1024 + tid * 4] = o;
}

// ------------------------------------------------------------------
extern "C" void kernel_launch(void* const* d_in, const int* in_sizes, int n_in,
                              void* d_out, int out_size, void* d_ws, size_t ws_size,
                              hipStream_t stream) {
  (void)in_sizes; (void)n_in; (void)out_size; (void)ws_size;
  const float* x   = (const float*)d_in[0];
  const float* wq  = (const float*)d_in[1];
  const float* bq  = (const float*)d_in[2];
  const float* wk  = (const float*)d_in[3];
  const float* bk  = (const float*)d_in[4];
  const float* wv  = (const float*)d_in[5];
  const float* bv  = (const float*)d_in[6];
  const float* wl  = (const float*)d_in[7];
  const float* bl  = (const float*)d_in[8];
  const float* lng = (const float*)d_in[9];
  const float* lnb = (const float*)d_in[10];

  const size_t MB = (size_t)1 << 20;
  char* ws = (char*)d_ws;
  bf16* xb    = (bf16*)(ws);             // 8 MB  [0,8)
  bf16* wqkvb = (bf16*)(ws + 8 * MB);    // 6 MB  [8,14)
  bf16* wlb   = (bf16*)(ws + 14 * MB);   // 2 MB  [14,16)
  bf16* Qb    = (bf16*)(ws + 16 * MB);   // 8 MB  [16,24)
  bf16* Kb    = (bf16*)(ws + 24 * MB);   // 8 MB  [24,32)
  bf16* VTb   = (bf16*)(ws + 32 * MB);   // 8 MB  [32,40)
  bf16* attb  = (bf16*)(ws + 40 * MB);   // 8 MB  [40,48)
  bf16* Y     = (bf16*)(ws + 16 * MB);   // 8 MB  [16,24) reuse: Q dead post-attn

  k_convert<<<dim3(8192), dim3(256), 0, stream>>>(x, wq, wk, wv, wl, xb, wqkvb, wlb);
  k_gemm_qkv<<<dim3(24, 32), dim3(256), 0, stream>>>(wqkvb, xb, bq, bk, bv, Qb, Kb, VTb);
  k_attn<<<dim3(64, 8), dim3(256), 0, stream>>>(Qb, Kb, VTb, x, attb);
  k_gemm_out<<<dim3(16, 32), dim3(256), 0, stream>>>(wlb, attb, bl, Y);
  k_ln<<<dim3(4096), dim3(256), 0, stream>>>(Y, lng, lnb, (float*)d_out);
}

// Round 13
// 104.515 us; speedup vs baseline: 1.0507x; 1.0044x over previous
//
#include <hip/hip_runtime.h>
#include <cstdint>
#include <cstddef>

typedef __bf16 bf16;
typedef __bf16 bf16x4_t __attribute__((ext_vector_type(4)));
typedef __bf16 bf16x8_t __attribute__((ext_vector_type(8)));
typedef float f32x4_t __attribute__((ext_vector_type(4)));

#define DEV static __device__ __forceinline__

DEV void gload16(const void* g, void* l) {
  __builtin_amdgcn_global_load_lds((const __attribute__((address_space(1))) void*)g,
                                   (__attribute__((address_space(3))) void*)l, 16, 0, 0);
}

DEV f32x4_t mfma16(bf16x8_t a, bf16x8_t b, f32x4_t c) {
  return __builtin_amdgcn_mfma_f32_16x16x32_bf16(a, b, c, 0, 0, 0);
}

#define BAR __builtin_amdgcn_s_barrier()
#define FENCE asm volatile("" ::: "memory")
#define VMC(n) asm volatile("s_waitcnt vmcnt(" #n ")" ::: "memory")

// ------------------------------------------------------------------
// Kernel 1: fp32 -> bf16 conversion of x and weights (unchanged).
// ------------------------------------------------------------------
__global__ __launch_bounds__(256) void k_convert(
    const float* __restrict__ x, const float* __restrict__ wq,
    const float* __restrict__ wk, const float* __restrict__ wv,
    const float* __restrict__ wl,
    bf16* __restrict__ xb, bf16* __restrict__ wqkvb, bf16* __restrict__ wlb) {
  const size_t M1 = (size_t)1 << 20;
  size_t i = ((size_t)blockIdx.x * 256 + threadIdx.x) * 4;
  const float* src; bf16* dst; size_t off;
  if (i < 4 * M1)      { src = x;  dst = xb;           off = i; }
  else if (i < 5 * M1) { src = wq; dst = wqkvb;        off = i - 4 * M1; }
  else if (i < 6 * M1) { src = wk; dst = wqkvb + M1;   off = i - 5 * M1; }
  else if (i < 7 * M1) { src = wv; dst = wqkvb + 2*M1; off = i - 6 * M1; }
  else                 { src = wl; dst = wlb;          off = i - 7 * M1; }
  f32x4_t v = *(const f32x4_t*)&src[off];
  bf16x4_t o;
  o[0] = (bf16)v[0]; o[1] = (bf16)v[1]; o[2] = (bf16)v[2]; o[3] = (bf16)v[3];
  *(bf16x4_t*)&dst[off] = o;
}

// ------------------------------------------------------------------
// Kernel 2: QKV projection (unchanged — parked at structure ceiling).
// ------------------------------------------------------------------
__global__ __launch_bounds__(256) void k_gemm_qkv(
    const bf16* __restrict__ W, const bf16* __restrict__ Xb,
    const float* __restrict__ bq, const float* __restrict__ bk,
    const float* __restrict__ bv,
    bf16* __restrict__ Q, bf16* __restrict__ Kc, bf16* __restrict__ VT) {
  __shared__ alignas(16) bf16 smem[16384];
  bf16* lA = smem;
  bf16* lB = smem + 8192;
  const int tid = threadIdx.x, wave = tid >> 6, lane = tid & 63;
  const int wm = (wave >> 1) * 64, wn = (wave & 1) * 64;
  const int fr = lane & 15, fg = lane >> 4;
  const int csw = (((lane & 7) ^ (lane >> 3)) << 3);
  const int m0 = blockIdx.x * 128, n0 = blockIdx.y * 128;

  f32x4_t acc[4][4];
  const f32x4_t vzero = {0.f, 0.f, 0.f, 0.f};
#pragma unroll
  for (int a = 0; a < 4; ++a)
#pragma unroll
    for (int c = 0; c < 4; ++c) acc[a][c] = vzero;

  const int rowoff = wave * 8 + (lane >> 3);

  for (int kt = 0; kt < 16; ++kt) {
#pragma unroll
    for (int i = 0; i < 4; ++i) {
      gload16(W + (size_t)(m0 + i * 32 + rowoff) * 1024 + kt * 64 + csw,
              &lA[(i * 32 + wave * 8) * 64]);
      gload16(Xb + (size_t)(n0 + i * 32 + rowoff) * 1024 + kt * 64 + csw,
              &lB[(i * 32 + wave * 8) * 64]);
    }
    __syncthreads();
    bf16x8_t af[4][2], bfr[4][2];
#pragma unroll
    for (int mi = 0; mi < 4; ++mi)
#pragma unroll
      for (int ks = 0; ks < 2; ++ks) {
        const int r = wm + mi * 16 + fr;
        af[mi][ks] = *(const bf16x8_t*)
            &lA[r * 64 + ((((ks << 2) + fg) ^ (fr & 7)) << 3)];
      }
#pragma unroll
    for (int ni = 0; ni < 4; ++ni)
#pragma unroll
      for (int ks = 0; ks < 2; ++ks) {
        const int r = wn + ni * 16 + fr;
        bfr[ni][ks] = *(const bf16x8_t*)
            &lB[r * 64 + ((((ks << 2) + fg) ^ (fr & 7)) << 3)];
      }
    __builtin_amdgcn_s_setprio(1);
#pragma unroll
    for (int ks = 0; ks < 2; ++ks)
#pragma unroll
      for (int mi = 0; mi < 4; ++mi)
#pragma unroll
        for (int ni = 0; ni < 4; ++ni)
          acc[mi][ni] = mfma16(af[mi][ks], bfr[ni][ks], acc[mi][ni]);
    __builtin_amdgcn_s_setprio(0);
    __syncthreads();
  }

  const int region = m0 >> 10;
  const float* bp = (region == 0) ? bq : ((region == 1) ? bk : bv);
  if (region < 2) {
    bf16* QK = (region == 0) ? Q : Kc;
#pragma unroll
    for (int mi = 0; mi < 4; ++mi) {
      const int f = (m0 & 1023) + wm + mi * 16 + fg * 4;
      const int h = f >> 6, d = f & 63;
#pragma unroll
      for (int ni = 0; ni < 4; ++ni) {
        const int t = n0 + wn + ni * 16 + fr;
        const int b = t >> 10, s = t & 1023;
        const int bh = b * 16 + h;
        f32x4_t v = acc[mi][ni];
        bf16x4_t o;
#pragma unroll
        for (int j = 0; j < 4; ++j) o[j] = (bf16)(v[j] + bp[f + j]);
        *(bf16x4_t*)&QK[((size_t)bh * 1024 + s) * 64 + d] = o;
      }
    }
  } else {
#pragma unroll
    for (int mi = 0; mi < 4; ++mi) {
      const int dl = wm + mi * 16 + fg * 4;
      const int floc = (m0 & 1023) + dl;
#pragma unroll
      for (int ni = 0; ni < 4; ++ni) {
        const int sl = wn + ni * 16 + fr;
        f32x4_t v = acc[mi][ni];
#pragma unroll
        for (int j = 0; j < 4; ++j) {
          const int d = dl + j;
          smem[d * 128 + (sl ^ ((d & 7) << 3))] = (bf16)(v[j] + bp[floc + j]);
        }
      }
    }
    __syncthreads();
    const int b = n0 >> 10;
#pragma unroll
    for (int i = 0; i < 8; ++i) {
      const int d = i * 16 + (tid >> 4);
      const int c = tid & 15;
      bf16x8_t vv = *(const bf16x8_t*)&smem[d * 128 + ((c ^ (d & 7)) << 3)];
      const int floc = (m0 & 1023) + d;
      const int h = floc >> 6, dd = floc & 63;
      const int sg = (n0 & 1023) + c * 8;
      *(bf16x8_t*)&VT[((size_t)(b * 16 + h) * 64 + dd) * 1024 + sg] = vv;
    }
  }
}

// ------------------------------------------------------------------
// Kernel 3: swapped-QK^T in-register-P attention — r10 scalar
// epilogue restored (LDS-transpose epilogue was perf-neutral and
// cost +0.012 absmax from the extra O rounding); lsum4 ILP kept.
// ------------------------------------------------------------------
__global__ __launch_bounds__(256) void k_attn(
    const bf16* __restrict__ Q, const bf16* __restrict__ K,
    const bf16* __restrict__ VT, const float* __restrict__ X,
    bf16* __restrict__ ATTB) {
  __shared__ alignas(16) bf16 sm[16384];   // lK[2] | lV[2], 32 KB
  const int tid = threadIdx.x, wave = tid >> 6, lane = tid & 63;
  const int bh = blockIdx.x, qt = blockIdx.y;
  const int q0 = qt * 128 + wave * 32;
  const int fr = lane & 15, fg = lane >> 4;
  const int rx = (fr & 7) << 3;
  const f32x4_t vzero = {0.f, 0.f, 0.f, 0.f};

  bf16x8_t qf[2][2];
#pragma unroll
  for (int qi = 0; qi < 2; ++qi)
#pragma unroll
    for (int ks = 0; ks < 2; ++ks)
      qf[qi][ks] = *(const bf16x8_t*)
          &Q[((size_t)bh * 1024 + q0 + qi * 16 + fr) * 64 + ks * 32 + fg * 8];

  f32x4_t oacc[2][4];
  f32x4_t lsum4[2] = {vzero, vzero};
#pragma unroll
  for (int qi = 0; qi < 2; ++qi)
#pragma unroll
    for (int dj = 0; dj < 4; ++dj) oacc[qi][dj] = vzero;

  const int srow = lane >> 3;
  const int scolsw = (((lane & 7) ^ srow) * 8);

  auto STAGE = [&](int buf, int kv) {
    bf16* dK = sm + buf * 4096;
    bf16* dV = sm + 8192 + buf * 4096;
#pragma unroll
    for (int i = 0; i < 2; ++i) {
      const int c = wave * 2 + i;
      gload16(&K[((size_t)bh * 1024 + kv * 64 + c * 8 + srow) * 64 + scolsw],
              &dK[c * 512]);
      gload16(&VT[((size_t)bh * 64 + c * 8 + srow) * 1024 + kv * 64 + scolsw],
              &dV[c * 512]);
    }
  };

  auto TILE = [&](int cur) {
    const bf16* sK = sm + cur * 4096;
    const bf16* sV = sm + 8192 + cur * 4096;
    bf16x8_t kb[4][2];
#pragma unroll
    for (int kj = 0; kj < 4; ++kj)
#pragma unroll
      for (int ks = 0; ks < 2; ++ks) {
        const int r = kj * 16 + fr;
        kb[kj][ks] = *(const bf16x8_t*)&sK[r * 64 + ((ks * 32 + fg * 8) ^ rx)];
      }
    f32x4_t s[2][4];
#pragma unroll
    for (int qi = 0; qi < 2; ++qi)
#pragma unroll
      for (int kj = 0; kj < 4; ++kj) {
        f32x4_t z = vzero;
#pragma unroll
        for (int ks = 0; ks < 2; ++ks) z = mfma16(kb[kj][ks], qf[qi][ks], z);
        s[qi][kj] = z;
      }

    bf16x8_t vb[4][2];
#pragma unroll
    for (int dj = 0; dj < 4; ++dj)
#pragma unroll
      for (int ks = 0; ks < 2; ++ks) {
        const int r = dj * 16 + fr;
        const int c0 = ks * 32 + fg * 4;
        const int e0 = (c0 & 7) | ((((c0 >> 3) ^ (r & 7))) << 3);
        const int c1 = c0 + 16;
        const int e1 = (c1 & 7) | ((((c1 >> 3) ^ (r & 7))) << 3);
        bf16x4_t lo = *(const bf16x4_t*)&sV[r * 64 + e0];
        bf16x4_t hi = *(const bf16x4_t*)&sV[r * 64 + e1];
        bf16x8_t vv;
#pragma unroll
        for (int j = 0; j < 4; ++j) { vv[j] = lo[j]; vv[4 + j] = hi[j]; }
        vb[dj][ks] = vv;
      }

    bf16x8_t paf[2][2];
#pragma unroll
    for (int qi = 0; qi < 2; ++qi)
#pragma unroll
      for (int ks = 0; ks < 2; ++ks) {
        bf16x8_t pv;
#pragma unroll
        for (int h2 = 0; h2 < 2; ++h2)
#pragma unroll
          for (int j = 0; j < 4; ++j) {
            bf16 pb = (bf16)__expf(s[qi][2 * ks + h2][j]);
            lsum4[qi][j] += (float)pb;
            pv[h2 * 4 + j] = pb;
          }
        paf[qi][ks] = pv;
      }

#pragma unroll
    for (int qi = 0; qi < 2; ++qi)
#pragma unroll
      for (int dj = 0; dj < 4; ++dj)
#pragma unroll
        for (int ks = 0; ks < 2; ++ks)
          oacc[qi][dj] = mfma16(paf[qi][ks], vb[dj][ks], oacc[qi][dj]);
  };

  STAGE(0, 0);
  STAGE(1, 1);
  for (int kv = 0; kv < 15; ++kv) {
    VMC(4); BAR; FENCE;
    TILE(kv & 1);
    BAR; FENCE;
    if (kv < 14) STAGE(kv & 1, kv + 2);
  }
  VMC(0); BAR; FENCE;
  TILE(1);

  float lsum[2];
#pragma unroll
  for (int qi = 0; qi < 2; ++qi) {
    lsum[qi] = (lsum4[qi][0] + lsum4[qi][1]) + (lsum4[qi][2] + lsum4[qi][3]);
    lsum[qi] += __shfl_xor(lsum[qi], 16);
    lsum[qi] += __shfl_xor(lsum[qi], 32);
  }
  float rs[2][4];
#pragma unroll
  for (int qi = 0; qi < 2; ++qi)
#pragma unroll
    for (int j = 0; j < 4; ++j)
      rs[qi][j] = __shfl(lsum[qi], fg * 4 + j);

  // scalar epilogue (r10): single rounding of (O/l*0.125 + x)
  const int b = bh >> 4, h = bh & 15;
#pragma unroll
  for (int qi = 0; qi < 2; ++qi)
#pragma unroll
    for (int dj = 0; dj < 4; ++dj)
#pragma unroll
      for (int j = 0; j < 4; ++j) {
        const int s_ = q0 + qi * 16 + fg * 4 + j;
        const int d_ = dj * 16 + fr;
        const size_t tok = (size_t)b * 1024 + s_;
        const size_t fidx = (size_t)h * 64 + d_;
        float val = oacc[qi][dj][j] / rs[qi][j] * 0.125f + X[tok * 1024 + fidx];
        ATTB[tok * 1024 + fidx] = (bf16)val;
      }
}

// ------------------------------------------------------------------
// Kernel 4 (REWORKED): output projection with 64(M)x128(N) tiles ->
// grid (16,32) = 512 blocks = 2 blocks/CU (was 256 = 1/CU: no TLP
// backfill through barriers — the r4 lesson applied to this kernel).
// Same 2-phase dbuf + counted vmcnt + swizzle; 6 gloads/wave/stage
// (2 A-chunks + 4 B-chunks) -> vmcnt(6). LDS 48 KB -> 2 blocks/CU.
// ------------------------------------------------------------------
__global__ __launch_bounds__(256, 2) void k_gemm_out(
    const bf16* __restrict__ Wl, const bf16* __restrict__ Ax,
    const float* __restrict__ bl, bf16* __restrict__ Y) {
  __shared__ alignas(16) bf16 lA[2][64 * 64];
  __shared__ alignas(16) bf16 lB[2][128 * 64];
  const int tid = threadIdx.x, wave = tid >> 6, lane = tid & 63;
  const int wm = (wave >> 1) * 32, wn = (wave & 1) * 64;
  const int fr = lane & 15, fg = lane >> 4;
  const int srow = lane >> 3;
  const int csw = (((lane & 7) ^ srow) << 3);
  const int m0 = blockIdx.x * 64, n0 = blockIdx.y * 128;

  f32x4_t acc[2][4];
  const f32x4_t vzero = {0.f, 0.f, 0.f, 0.f};
#pragma unroll
  for (int a = 0; a < 2; ++a)
#pragma unroll
    for (int c = 0; c < 4; ++c) acc[a][c] = vzero;

  auto STAGE = [&](int buf, int kt) {
#pragma unroll
    for (int i = 0; i < 2; ++i)   // A: 2 chunks of 8 rows per wave
      gload16(Wl + (size_t)(m0 + wave * 16 + i * 8 + srow) * 1024 + kt * 64 + csw,
              &lA[buf][(wave * 16 + i * 8) * 64]);
#pragma unroll
    for (int i = 0; i < 4; ++i)   // B: 4 chunks of 8 rows per wave
      gload16(Ax + (size_t)(n0 + wave * 32 + i * 8 + srow) * 1024 + kt * 64 + csw,
              &lB[buf][(wave * 32 + i * 8) * 64]);
  };

  auto COMPUTE = [&](int buf) {
    bf16x8_t af[2][2], bfr[4][2];
#pragma unroll
    for (int mi = 0; mi < 2; ++mi)
#pragma unroll
      for (int ks = 0; ks < 2; ++ks) {
        const int r = wm + mi * 16 + fr;
        af[mi][ks] = *(const bf16x8_t*)
            &lA[buf][r * 64 + ((((ks << 2) + fg) ^ (fr & 7)) << 3)];
      }
#pragma unroll
    for (int ni = 0; ni < 4; ++ni)
#pragma unroll
      for (int ks = 0; ks < 2; ++ks) {
        const int r = wn + ni * 16 + fr;
        bfr[ni][ks] = *(const bf16x8_t*)
            &lB[buf][r * 64 + ((((ks << 2) + fg) ^ (fr & 7)) << 3)];
      }
    __builtin_amdgcn_s_setprio(1);
#pragma unroll
    for (int ks = 0; ks < 2; ++ks)
#pragma unroll
      for (int mi = 0; mi < 2; ++mi)
#pragma unroll
        for (int ni = 0; ni < 4; ++ni)
          acc[mi][ni] = mfma16(af[mi][ks], bfr[ni][ks], acc[mi][ni]);
    __builtin_amdgcn_s_setprio(0);
  };

  STAGE(0, 0);
  STAGE(1, 1);
  for (int t = 0; t < 15; ++t) {
    asm volatile("s_waitcnt vmcnt(6)" ::: "memory");
    __builtin_amdgcn_s_barrier();
    COMPUTE(t & 1);
    __builtin_amdgcn_s_barrier();
    if (t < 14) STAGE(t & 1, t + 2);
  }
  asm volatile("s_waitcnt vmcnt(0)" ::: "memory");
  __builtin_amdgcn_s_barrier();
  COMPUTE(1);

#pragma unroll
  for (int mi = 0; mi < 2; ++mi) {
    const int f = m0 + wm + mi * 16 + fg * 4;
#pragma unroll
    for (int ni = 0; ni < 4; ++ni) {
      const int t = n0 + wn + ni * 16 + fr;
      f32x4_t v = acc[mi][ni];
      bf16x4_t o;
#pragma unroll
      for (int j = 0; j < 4; ++j) o[j] = (bf16)(v[j] + bl[f + j]);
      *(bf16x4_t*)&Y[(size_t)t * 1024 + f] = o;
    }
  }
}

// ------------------------------------------------------------------
// Kernel 5: LayerNorm (unchanged; reads bf16 Y).
// ------------------------------------------------------------------
__global__ __launch_bounds__(256) void k_ln(
    const bf16* __restrict__ Y, const float* __restrict__ g,
    const float* __restrict__ bta, float* __restrict__ OUT) {
  const int row = blockIdx.x, tid = threadIdx.x;
  const bf16* y = Y + (size_t)row * 1024;
  bf16x4_t yv = *(const bf16x4_t*)&y[tid * 4];
  f32x4_t v;
#pragma unroll
  for (int j = 0; j < 4; ++j) v[j] = (float)yv[j];
  float s = v[0] + v[1] + v[2] + v[3];
  float s2 = v[0]*v[0] + v[1]*v[1] + v[2]*v[2] + v[3]*v[3];
#pragma unroll
  for (int m = 1; m < 64; m <<= 1) {
    s += __shfl_xor(s, m);
    s2 += __shfl_xor(s2, m);
  }
  __shared__ float ps[4], ps2[4];
  const int wave = tid >> 6, lane = tid & 63;
  if (lane == 0) { ps[wave] = s; ps2[wave] = s2; }
  __syncthreads();
  s = ps[0] + ps[1] + ps[2] + ps[3];
  s2 = ps2[0] + ps2[1] + ps2[2] + ps2[3];
  const float mu = s * (1.f / 1024.f);
  const float var = s2 * (1.f / 1024.f) - mu * mu;
  const float rs = rsqrtf(var + 1e-5f);
  f32x4_t gg = *(const f32x4_t*)&g[tid * 4];
  f32x4_t bb = *(const f32x4_t*)&bta[tid * 4];
  f32x4_t o;
#pragma unroll
  for (int j = 0; j < 4; ++j) o[j] = (v[j] - mu) * rs * gg[j] + bb[j];
  *(f32x4_t*)&OUT[(size_t)row * 1024 + tid * 4] = o;
}

// ------------------------------------------------------------------
extern "C" void kernel_launch(void* const* d_in, const int* in_sizes, int n_in,
                              void* d_out, int out_size, void* d_ws, size_t ws_size,
                              hipStream_t stream) {
  (void)in_sizes; (void)n_in; (void)out_size; (void)ws_size;
  const float* x   = (const float*)d_in[0];
  const float* wq  = (const float*)d_in[1];
  const float* bq  = (const float*)d_in[2];
  const float* wk  = (const float*)d_in[3];
  const float* bk  = (const float*)d_in[4];
  const float* wv  = (const float*)d_in[5];
  const float* bv  = (const float*)d_in[6];
  const float* wl  = (const float*)d_in[7];
  const float* bl  = (const float*)d_in[8];
  const float* lng = (const float*)d_in[9];
  const float* lnb = (const float*)d_in[10];

  const size_t MB = (size_t)1 << 20;
  char* ws = (char*)d_ws;
  bf16* xb    = (bf16*)(ws);             // 8 MB  [0,8)
  bf16* wqkvb = (bf16*)(ws + 8 * MB);    // 6 MB  [8,14)
  bf16* wlb   = (bf16*)(ws + 14 * MB);   // 2 MB  [14,16)
  bf16* Qb    = (bf16*)(ws + 16 * MB);   // 8 MB  [16,24)
  bf16* Kb    = (bf16*)(ws + 24 * MB);   // 8 MB  [24,32)
  bf16* VTb   = (bf16*)(ws + 32 * MB);   // 8 MB  [32,40)
  bf16* attb  = (bf16*)(ws + 40 * MB);   // 8 MB  [40,48)
  bf16* Y     = (bf16*)(ws + 16 * MB);   // 8 MB  [16,24) reuse: Q dead post-attn

  k_convert<<<dim3(8192), dim3(256), 0, stream>>>(x, wq, wk, wv, wl, xb, wqkvb, wlb);
  k_gemm_qkv<<<dim3(24, 32), dim3(256), 0, stream>>>(wqkvb, xb, bq, bk, bv, Qb, Kb, VTb);
  k_attn<<<dim3(64, 8), dim3(256), 0, stream>>>(Qb, Kb, VTb, x, attb);
  k_gemm_out<<<dim3(16, 32), dim3(256), 0, stream>>>(wlb, attb, bl, Y);
  k_ln<<<dim3(4096), dim3(256), 0, stream>>>(Y, lng, lnb, (float*)d_out);
}